// Round 1
// baseline (67.191 us; speedup 1.0000x reference)
//
#include <hip/hip_runtime.h>
#include <hip/hip_bf16.h>
#include <stdint.h>

#define N_ROWS 4096
#define D_DIM  256
#define TWO_N  8192

typedef __attribute__((ext_vector_type(8))) short short8;
typedef __attribute__((ext_vector_type(4))) float f32x4;

__device__ __forceinline__ unsigned bf16rne(float f) {
    unsigned u = __float_as_uint(f);
    return (u + 0x7fffu + ((u >> 16) & 1u)) >> 16;
}

// ---------------- K1: L2-normalize rows, write bf16 reps [8192][256] ----------------
__global__ __launch_bounds__(256) void knorm(const float* __restrict__ zi,
                                             const float* __restrict__ zj,
                                             unsigned short* __restrict__ reps) {
    int wave = threadIdx.x >> 6, lane = threadIdx.x & 63;
    int row = blockIdx.x * 4 + wave;                  // 0..8191
    const float* src = (row < N_ROWS) ? (zi + (size_t)row * D_DIM)
                                      : (zj + (size_t)(row - N_ROWS) * D_DIM);
    float4 v = *(const float4*)(src + lane * 4);
    float ss = v.x * v.x + v.y * v.y + v.z * v.z + v.w * v.w;
#pragma unroll
    for (int m = 1; m < 64; m <<= 1) ss += __shfl_xor(ss, m, 64);
    float scale = 1.0f / fmaxf(sqrtf(ss), 1e-12f);
    unsigned b0 = bf16rne(v.x * scale), b1 = bf16rne(v.y * scale);
    unsigned b2 = bf16rne(v.z * scale), b3 = bf16rne(v.w * scale);
    uint2 o;
    o.x = b0 | (b1 << 16);
    o.y = b2 | (b3 << 16);
    *(uint2*)(reps + (size_t)row * D_DIM + lane * 4) = o;
}

// ---------------- K2: exact f32 positive-pair sims ----------------
__global__ __launch_bounds__(64) void kpos(const float* __restrict__ zi,
                                           const float* __restrict__ zj,
                                           float* __restrict__ pos) {
    int k = blockIdx.x;
    int lane = threadIdx.x;
    float4 a = *(const float4*)(zi + (size_t)k * D_DIM + lane * 4);
    float4 b = *(const float4*)(zj + (size_t)k * D_DIM + lane * 4);
    float dij = a.x * b.x + a.y * b.y + a.z * b.z + a.w * b.w;
    float dii = a.x * a.x + a.y * a.y + a.z * a.z + a.w * a.w;
    float djj = b.x * b.x + b.y * b.y + b.z * b.z + b.w * b.w;
#pragma unroll
    for (int m = 1; m < 64; m <<= 1) {
        dij += __shfl_xor(dij, m, 64);
        dii += __shfl_xor(dii, m, 64);
        djj += __shfl_xor(djj, m, 64);
    }
    if (lane == 0) {
        float p = dij / (fmaxf(sqrtf(dii), 1e-12f) * fmaxf(sqrtf(djj), 1e-12f)) * 2.0f;
        pos[k] = p;
        pos[k + N_ROWS] = p;
    }
}

// ---------------- K3: fused sim GEMM + exp row-sum ----------------
// grid: 64 row-tiles (BM=128) x 8 col-splits (1024 cols each). 256 threads = 4 waves,
// each wave owns 32 rows (2 row-frags of 16). Column tiles of 64 staged in LDS.
__global__ __launch_bounds__(256) void kmain(const unsigned short* __restrict__ reps,
                                             float* __restrict__ rowsum) {
    __shared__ __align__(16) char ldsB[64 * 512];   // 64 cols x 256 k bf16, slot-swizzled

    const int rt = blockIdx.x >> 3;          // 0..63
    const int cs = blockIdx.x & 7;           // 0..7
    const int tid = threadIdx.x;
    const int wave = tid >> 6, lane = tid & 63;
    const int l15 = lane & 15, lhi = lane >> 4;

    const int rowbaseW = rt * 128 + wave * 32;

    // A fragments in registers: 2 row-frags x 8 k-steps, 16B each
    short8 afrag[2][8];
#pragma unroll
    for (int rf = 0; rf < 2; ++rf) {
        const char* arow = (const char*)reps + (size_t)(rowbaseW + rf * 16 + l15) * 512;
#pragma unroll
        for (int ks = 0; ks < 8; ++ks)
            afrag[rf][ks] = *(const short8*)(arow + ks * 64 + lhi * 16);
    }

    float sumexp[2][4];
#pragma unroll
    for (int rf = 0; rf < 2; ++rf)
#pragma unroll
        for (int r = 0; r < 4; ++r) sumexp[rf][r] = 0.0f;

    const char* repsb = (const char*)reps;

    for (int ct = 0; ct < 16; ++ct) {
        const int colbase = cs * 1024 + ct * 64;

        // stage B tile [64 cols][512 B] with slot XOR-swizzle (slot ^= row&7)
#pragma unroll
        for (int i = 0; i < 8; ++i) {
            int o = tid * 16 + i * 4096;
            int row = o >> 9;
            int slot = (o >> 4) & 31;
            uint4 v = *(const uint4*)(repsb + (size_t)(colbase + row) * 512 + slot * 16);
            int dslot = slot ^ (row & 7);
            *(uint4*)(ldsB + row * 512 + dslot * 16) = v;
        }
        __syncthreads();

        f32x4 acc[2][4];
#pragma unroll
        for (int rf = 0; rf < 2; ++rf)
#pragma unroll
            for (int cf = 0; cf < 4; ++cf) acc[rf][cf] = (f32x4){0.f, 0.f, 0.f, 0.f};

#pragma unroll
        for (int ks = 0; ks < 8; ++ks) {
            short8 b[4];
#pragma unroll
            for (int cf = 0; cf < 4; ++cf) {
                int col = cf * 16 + l15;
                int slot = ks * 4 + lhi;
                int ds = slot ^ (col & 7);
                b[cf] = *(const short8*)(ldsB + col * 512 + ds * 16);
            }
#pragma unroll
            for (int rf = 0; rf < 2; ++rf)
#pragma unroll
                for (int cf = 0; cf < 4; ++cf)
                    acc[rf][cf] = __builtin_amdgcn_mfma_f32_16x16x32_bf16(
                        afrag[rf][ks], b[cf], acc[rf][cf], 0, 0, 0);
        }

        // epilogue: exp + accumulate row sums (mask diagonal)
        bool has_diag = (colbase < rowbaseW + 32) && (rowbaseW < colbase + 64);
        if (has_diag) {
#pragma unroll
            for (int rf = 0; rf < 2; ++rf)
#pragma unroll
                for (int cf = 0; cf < 4; ++cf) {
                    f32x4 c = acc[rf][cf];
                    int gcol = colbase + cf * 16 + l15;
#pragma unroll
                    for (int r = 0; r < 4; ++r) {
                        int grow = rowbaseW + rf * 16 + lhi * 4 + r;
                        float e = __expf(2.0f * c[r]);
                        sumexp[rf][r] += (grow != gcol) ? e : 0.0f;
                    }
                }
        } else {
#pragma unroll
            for (int rf = 0; rf < 2; ++rf)
#pragma unroll
                for (int cf = 0; cf < 4; ++cf) {
                    f32x4 c = acc[rf][cf];
#pragma unroll
                    for (int r = 0; r < 4; ++r)
                        sumexp[rf][r] += __expf(2.0f * c[r]);
                }
        }
        __syncthreads();
    }

    // reduce the 16 lanes that share each row, one atomic per row
#pragma unroll
    for (int rf = 0; rf < 2; ++rf)
#pragma unroll
        for (int r = 0; r < 4; ++r) {
            float s = sumexp[rf][r];
            s += __shfl_xor(s, 1, 64);
            s += __shfl_xor(s, 2, 64);
            s += __shfl_xor(s, 4, 64);
            s += __shfl_xor(s, 8, 64);
            if (l15 == 0)
                atomicAdd(&rowsum[rowbaseW + rf * 16 + lhi * 4 + r], s);
        }
}

// ---------------- K4: loss = mean(log(rowsum) - pos) ----------------
__global__ __launch_bounds__(256) void kfinal(const float* __restrict__ rowsum,
                                              const float* __restrict__ pos,
                                              float* __restrict__ out) {
    __shared__ float red[4];
    float local = 0.0f;
    for (int r = threadIdx.x; r < TWO_N; r += 256)
        local += logf(rowsum[r]) - pos[r];
#pragma unroll
    for (int m = 1; m < 64; m <<= 1) local += __shfl_xor(local, m, 64);
    if ((threadIdx.x & 63) == 0) red[threadIdx.x >> 6] = local;
    __syncthreads();
    if (threadIdx.x == 0)
        out[0] = (red[0] + red[1] + red[2] + red[3]) * (1.0f / (float)TWO_N);
}

extern "C" void kernel_launch(void* const* d_in, const int* in_sizes, int n_in,
                              void* d_out, int out_size, void* d_ws, size_t ws_size,
                              hipStream_t stream) {
    const float* zi = (const float*)d_in[0];
    const float* zj = (const float*)d_in[1];
    float* out = (float*)d_out;

    unsigned short* reps = (unsigned short*)d_ws;                       // 8192*256 bf16 = 4 MiB
    float* rowsum = (float*)((char*)d_ws + (size_t)TWO_N * D_DIM * 2);  // 32 KiB
    float* pos = rowsum + TWO_N;                                        // 32 KiB

    hipMemsetAsync(rowsum, 0, TWO_N * sizeof(float), stream);
    knorm<<<2048, 256, 0, stream>>>(zi, zj, reps);
    kpos<<<N_ROWS, 64, 0, stream>>>(zi, zj, pos);
    kmain<<<512, 256, 0, stream>>>(reps, rowsum);
    kfinal<<<1, 256, 0, stream>>>(rowsum, pos, out);
}

// Round 2
// 61.837 us; speedup vs baseline: 1.0866x; 1.0866x over previous
//
#include <hip/hip_runtime.h>
#include <hip/hip_bf16.h>
#include <stdint.h>

#define N_ROWS 4096
#define D_DIM  256
#define TWO_N  8192
#define ROWB   512   // bytes per bf16 row (256 * 2)

typedef __attribute__((ext_vector_type(8))) short short8;
typedef __attribute__((ext_vector_type(16))) float f32x16;

#define GLOBAL_AS __attribute__((address_space(1)))
#define LDS_AS    __attribute__((address_space(3)))

__device__ __forceinline__ unsigned bf16rne(float f) {
    unsigned u = __float_as_uint(f);
    return (u + 0x7fffu + ((u >> 16) & 1u)) >> 16;
}

// ---------- K1: fused normalize (bf16 reps) + exact positive-pair sims + rowsum zero ----------
// 1024 blocks x 256 threads; each wave handles one pair k (rows k and k+N).
__global__ __launch_bounds__(256) void kprep(const float* __restrict__ zi,
                                             const float* __restrict__ zj,
                                             unsigned short* __restrict__ reps,
                                             float* __restrict__ pos,
                                             float* __restrict__ rowsum) {
    int wave = threadIdx.x >> 6, lane = threadIdx.x & 63;
    int k = blockIdx.x * 4 + wave;   // 0..4095
    float4 a = *(const float4*)(zi + (size_t)k * D_DIM + lane * 4);
    float4 b = *(const float4*)(zj + (size_t)k * D_DIM + lane * 4);
    float dii = a.x * a.x + a.y * a.y + a.z * a.z + a.w * a.w;
    float djj = b.x * b.x + b.y * b.y + b.z * b.z + b.w * b.w;
    float dij = a.x * b.x + a.y * b.y + a.z * b.z + a.w * b.w;
#pragma unroll
    for (int m = 1; m < 64; m <<= 1) {
        dii += __shfl_xor(dii, m, 64);
        djj += __shfl_xor(djj, m, 64);
        dij += __shfl_xor(dij, m, 64);
    }
    float si = 1.0f / fmaxf(sqrtf(dii), 1e-12f);
    float sj = 1.0f / fmaxf(sqrtf(djj), 1e-12f);
    {
        unsigned b0 = bf16rne(a.x * si), b1 = bf16rne(a.y * si);
        unsigned b2 = bf16rne(a.z * si), b3 = bf16rne(a.w * si);
        uint2 o; o.x = b0 | (b1 << 16); o.y = b2 | (b3 << 16);
        *(uint2*)(reps + (size_t)k * D_DIM + lane * 4) = o;
    }
    {
        unsigned b0 = bf16rne(b.x * sj), b1 = bf16rne(b.y * sj);
        unsigned b2 = bf16rne(b.z * sj), b3 = bf16rne(b.w * sj);
        uint2 o; o.x = b0 | (b1 << 16); o.y = b2 | (b3 << 16);
        *(uint2*)(reps + (size_t)(k + N_ROWS) * D_DIM + lane * 4) = o;
    }
    if (lane == 0) {
        float p = dij * si * sj * 2.0f;   // /TEMPERATURE
        pos[k] = p;
        pos[k + N_ROWS] = p;
    }
    if (threadIdx.x < 8) rowsum[blockIdx.x * 8 + threadIdx.x] = 0.0f;
}

// ---------- K2: fused sim GEMM (32x32x16 MFMA) + exp row-sums ----------
// grid 1024: rt = bid>>4 (64 row-tiles of BM=128), cs = bid&15 (512-col splits).
// 4 waves, each owns 32 rows. Col tiles of 64 staged in LDS via global_load_lds
// with pre-swizzled source: LDS[row][s] = G[row][s ^ (row&7)]  (16B slots).
__global__ __launch_bounds__(256) void kmain(const unsigned short* __restrict__ reps,
                                             float* __restrict__ rowsum) {
    __shared__ __align__(16) char ldsB[64 * ROWB];   // 32 KiB

    const int rt = blockIdx.x >> 4;
    const int cs = blockIdx.x & 15;
    const int tid = threadIdx.x;
    const int wave = tid >> 6, lane = tid & 63;
    const int l31 = lane & 31, lhi = lane >> 5;
    const int x7 = l31 & 7;
    const int rowbaseW = rt * 128 + wave * 32;
    const char* repsb = (const char*)reps;

    // A fragments: lane holds A[m=l31][k = ks*16 + lhi*8 + j]  (16B per ks)
    short8 afrag[16];
    {
        const char* arow = repsb + (size_t)(rowbaseW + l31) * ROWB + lhi * 16;
#pragma unroll
        for (int ks = 0; ks < 16; ++ks)
            afrag[ks] = *(const short8*)(arow + ks * 32);
    }

    float sumexp[16];
#pragma unroll
    for (int r = 0; r < 16; ++r) sumexp[r] = 0.0f;

    const int cb0 = (l31) * ROWB;        // LDS byte base, col-frag 0
    const int cb1 = (32 + l31) * ROWB;   // col-frag 1

    for (int ct = 0; ct < 8; ++ct) {
        const int colbase = cs * 512 + ct * 64;

        // stage 64 rows x 512B: 32 chunks of 1KB (2 rows each), 8 per wave
#pragma unroll
        for (int i = 0; i < 8; ++i) {
            int c = wave * 8 + i;                 // chunk 0..31 (wave-uniform)
            int row = 2 * c + lhi;                // per-lane row
            int gslot = l31 ^ (row & 7);          // inverse-swizzled source slot
            const char* gaddr = repsb + (size_t)(colbase + row) * ROWB + gslot * 16;
            __builtin_amdgcn_global_load_lds(
                (const GLOBAL_AS void*)gaddr,
                (LDS_AS void*)(ldsB + c * 1024), 16, 0, 0);
        }
        __syncthreads();   // waits vmcnt(0) for the gload_lds

        f32x16 acc0, acc1;
#pragma unroll
        for (int r = 0; r < 16; ++r) { acc0[r] = 0.0f; acc1[r] = 0.0f; }

#pragma unroll
        for (int ks = 0; ks < 16; ++ks) {
            int ds = ((2 * ks + lhi) ^ x7) * 16;  // swizzled 16B slot
            short8 b0 = *(const short8*)(ldsB + cb0 + ds);
            short8 b1 = *(const short8*)(ldsB + cb1 + ds);
            acc0 = __builtin_amdgcn_mfma_f32_32x32x16_bf16(afrag[ks], b0, acc0, 0, 0, 0);
            acc1 = __builtin_amdgcn_mfma_f32_32x32x16_bf16(afrag[ks], b1, acc1, 0, 0, 0);
        }

        // epilogue: exp(sim) accumulated per row; sim = 2*dot -> exp2(dot*2*log2e)
        const float C = 2.8853900817779268f;
        bool has_diag = (colbase < rowbaseW + 32) && (rowbaseW < colbase + 64);
        if (has_diag) {
            int gcol0 = colbase + l31, gcol1 = colbase + 32 + l31;
#pragma unroll
            for (int r = 0; r < 16; ++r) {
                int grow = rowbaseW + (r & 3) + 8 * (r >> 2) + 4 * lhi;
                float e0 = __builtin_amdgcn_exp2f(acc0[r] * C);
                float e1 = __builtin_amdgcn_exp2f(acc1[r] * C);
                sumexp[r] += (grow != gcol0) ? e0 : 0.0f;
                sumexp[r] += (grow != gcol1) ? e1 : 0.0f;
            }
        } else {
#pragma unroll
            for (int r = 0; r < 16; ++r) {
                sumexp[r] += __builtin_amdgcn_exp2f(acc0[r] * C);
                sumexp[r] += __builtin_amdgcn_exp2f(acc1[r] * C);
            }
        }
        __syncthreads();   // all reads done before next tile overwrites LDS
    }

    // reduce across the 32 lanes sharing each output row, one atomic per row
#pragma unroll
    for (int r = 0; r < 16; ++r) {
        float s = sumexp[r];
        s += __shfl_xor(s, 1, 64);
        s += __shfl_xor(s, 2, 64);
        s += __shfl_xor(s, 4, 64);
        s += __shfl_xor(s, 8, 64);
        s += __shfl_xor(s, 16, 64);
        if (l31 == 0)
            atomicAdd(&rowsum[rowbaseW + (r & 3) + 8 * (r >> 2) + 4 * lhi], s);
    }
}

// ---------- K3: loss = mean(log(rowsum) - pos) ----------
__global__ __launch_bounds__(1024) void kfinal(const float* __restrict__ rowsum,
                                               const float* __restrict__ pos,
                                               float* __restrict__ out) {
    __shared__ float red[16];
    float local = 0.0f;
    for (int r = threadIdx.x; r < TWO_N; r += 1024)
        local += __builtin_amdgcn_logf(rowsum[r]) * 0.6931471805599453f - pos[r];
#pragma unroll
    for (int m = 1; m < 64; m <<= 1) local += __shfl_xor(local, m, 64);
    if ((threadIdx.x & 63) == 0) red[threadIdx.x >> 6] = local;
    __syncthreads();
    if (threadIdx.x == 0) {
        float t = 0.0f;
#pragma unroll
        for (int i = 0; i < 16; ++i) t += red[i];
        out[0] = t * (1.0f / (float)TWO_N);
    }
}

extern "C" void kernel_launch(void* const* d_in, const int* in_sizes, int n_in,
                              void* d_out, int out_size, void* d_ws, size_t ws_size,
                              hipStream_t stream) {
    const float* zi = (const float*)d_in[0];
    const float* zj = (const float*)d_in[1];
    float* out = (float*)d_out;

    unsigned short* reps = (unsigned short*)d_ws;                       // 4 MiB
    float* rowsum = (float*)((char*)d_ws + (size_t)TWO_N * D_DIM * 2);  // 32 KiB
    float* pos = rowsum + TWO_N;                                        // 32 KiB

    kprep<<<1024, 256, 0, stream>>>(zi, zj, reps, pos, rowsum);
    kmain<<<1024, 256, 0, stream>>>(reps, rowsum);
    kfinal<<<1, 1024, 0, stream>>>(rowsum, pos, out);
}